// Round 11
// baseline (1011.974 us; speedup 1.0000x reference)
//
#include <hip/hip_runtime.h>
#include <hip/hip_cooperative_groups.h>
#include <math.h>

namespace cg = cooperative_groups;

#define Bn 16
#define Nn 1024
#define Dn 128

typedef unsigned short ushort;
typedef unsigned long long u64;
typedef short short8 __attribute__((ext_vector_type(8)));
typedef float f32x4 __attribute__((ext_vector_type(4)));
typedef ushort us8 __attribute__((ext_vector_type(8)));
typedef ushort us4 __attribute__((ext_vector_type(4)));

__device__ __forceinline__ ushort f2bf(float f) {
    unsigned u = __float_as_uint(f);
    u += 0x7fff + ((u >> 16) & 1);           // RTN-even
    return (ushort)(u >> 16);
}
__device__ __forceinline__ float bf2f(ushort s) {
    return __uint_as_float(((unsigned)s) << 16);
}

// Fragment layouts (us8 units), tile = 16 rows:
//   h16f/hA16f: unit = rt_global*256 + kc*64 + m*4 + q     (kc 0..3)
//   Ef:         unit = ((b*64 + rt)*32 + kc)*64 + m*4 + q  (kc 0..31)
//   Tf:         unit = ((b*8  + nt)*32 + kc)*64 + m*4 + q
// bm ballot layout: bm[(row_global*4 + chunk)*4 + j], chunk=col>>8, j=col&3, bit=(col>>2)&63

// ================= phase 0: weight split + Z init + adj ballot-pack =================
__device__ __forceinline__ void phase_wprep_pack(int L, int t,
        const float* __restrict__ Ww, const float* __restrict__ A,
        const float* __restrict__ adj,
        ushort* __restrict__ Whi, ushort* __restrict__ Wlo,
        ushort* __restrict__ AThi, ushort* __restrict__ ATlo,
        float* __restrict__ Z, u64* __restrict__ bm) {
    if (L < 64) {
        int i = L * 256 + t;
        float w = Ww[i];
        ushort wh = f2bf(w);
        Whi[i] = wh;
        Wlo[i] = f2bf(w - bf2f(wh));
        int e = i >> 7, d = i & 127;
        float a = A[d * Dn + e];
        ushort ah = f2bf(a);
        AThi[i] = ah;
        ATlo[i] = f2bf(a - bf2f(ah));
        Z[i] = (float)Nn;
    }
    int gwv = L * 4 + (t >> 6);
    int lane = t & 63;
    #pragma unroll 4
    for (int it = 0; it < 16; ++it) {
        int pair = gwv * 16 + it;                      // (row,chunk), 65536 total
        const float* p = adj + (size_t)pair * 256 + lane * 4;
        float4 v = *(const float4*)p;
        u64 b0 = __ballot(v.x > 0.f);
        u64 b1 = __ballot(v.y > 0.f);
        u64 b2 = __ballot(v.z > 0.f);
        u64 b3 = __ballot(v.w > 0.f);
        if (lane == 0) {
            u64* d = bm + (size_t)pair * 4;
            d[0] = b0; d[1] = b1; d[2] = b2; d[3] = b3;
        }
    }
}

// ================= phase 1: h = xW^T+b ; hA = hA ; fragment-layout bf16 out =================
__device__ __forceinline__ void phase_h(int L, int t, char* smem,
        const float* __restrict__ x, const float* __restrict__ Wb,
        const ushort* __restrict__ Whi, const ushort* __restrict__ Wlo,
        const ushort* __restrict__ AThi, const ushort* __restrict__ ATlo,
        float* __restrict__ h, ushort* __restrict__ h16f, ushort* __restrict__ hA16f) {
    int I0 = L * 16;
    int w = t >> 6, lane = t & 63;
    int m = lane & 15, q = lane >> 4;
    float (*hs)[Dn + 4]  = (float(*)[Dn + 4])smem;            // 8448 B
    float (*has)[Dn + 4] = (float(*)[Dn + 4])(smem + 8448);   // 8448 B

    const float* px = x + (size_t)(I0 + m) * Dn;
    f32x4 acc0 = {0,0,0,0}, acc1 = {0,0,0,0};
    #pragma unroll
    for (int ks = 0; ks < 4; ++ks) {
        int k0 = q * 8 + ks * 32;
        float v[8]; short8 ahi, alo;
        *(float4*)(v)     = *(const float4*)(px + k0);
        *(float4*)(v + 4) = *(const float4*)(px + k0 + 4);
        #pragma unroll
        for (int j = 0; j < 8; ++j) {
            ushort hi = f2bf(v[j]);
            ahi[j] = (short)hi;
            alo[j] = (short)f2bf(v[j] - bf2f(hi));
        }
        #pragma unroll
        for (int nn = 0; nn < 2; ++nn) {
            int brow = (w * 2 + nn) * 16 + m;
            short8 bhi = __builtin_bit_cast(short8, ((const us8*)(Whi + (size_t)brow * Dn))[q + ks * 4]);
            short8 blo = __builtin_bit_cast(short8, ((const us8*)(Wlo + (size_t)brow * Dn))[q + ks * 4]);
            f32x4 acc = nn ? acc1 : acc0;
            acc = __builtin_amdgcn_mfma_f32_16x16x32_bf16(ahi, bhi, acc, 0, 0, 0);
            acc = __builtin_amdgcn_mfma_f32_16x16x32_bf16(alo, bhi, acc, 0, 0, 0);
            acc = __builtin_amdgcn_mfma_f32_16x16x32_bf16(ahi, blo, acc, 0, 0, 0);
            if (nn) acc1 = acc; else acc0 = acc;
        }
    }
    #pragma unroll
    for (int nn = 0; nn < 2; ++nn) {
        int col = (w * 2 + nn) * 16 + m;
        float bias = Wb[col];
        f32x4 acc = nn ? acc1 : acc0;
        #pragma unroll
        for (int r = 0; r < 4; ++r) {
            int rl = q * 4 + r;
            float hv = acc[r] + bias;
            h[(size_t)(I0 + rl) * Dn + col] = hv;
            hs[rl][col] = hv;
        }
    }
    __syncthreads();

    f32x4 bcc0 = {0,0,0,0}, bcc1 = {0,0,0,0};
    #pragma unroll
    for (int ks = 0; ks < 4; ++ks) {
        int k0 = q * 8 + ks * 32;
        float v[8]; short8 ahi, alo;
        *(float4*)(v)     = *(const float4*)(&hs[m][k0]);
        *(float4*)(v + 4) = *(const float4*)(&hs[m][k0 + 4]);
        #pragma unroll
        for (int j = 0; j < 8; ++j) {
            ushort hi = f2bf(v[j]);
            ahi[j] = (short)hi;
            alo[j] = (short)f2bf(v[j] - bf2f(hi));
        }
        #pragma unroll
        for (int nn = 0; nn < 2; ++nn) {
            int brow = (w * 2 + nn) * 16 + m;
            short8 bhi = __builtin_bit_cast(short8, ((const us8*)(AThi + (size_t)brow * Dn))[q + ks * 4]);
            short8 blo = __builtin_bit_cast(short8, ((const us8*)(ATlo + (size_t)brow * Dn))[q + ks * 4]);
            f32x4 acc = nn ? bcc1 : bcc0;
            acc = __builtin_amdgcn_mfma_f32_16x16x32_bf16(ahi, bhi, acc, 0, 0, 0);
            acc = __builtin_amdgcn_mfma_f32_16x16x32_bf16(alo, bhi, acc, 0, 0, 0);
            acc = __builtin_amdgcn_mfma_f32_16x16x32_bf16(ahi, blo, acc, 0, 0, 0);
            if (nn) bcc1 = acc; else bcc0 = acc;
        }
    }
    #pragma unroll
    for (int nn = 0; nn < 2; ++nn) {
        int col = (w * 2 + nn) * 16 + m;
        f32x4 acc = nn ? bcc1 : bcc0;
        #pragma unroll
        for (int r = 0; r < 4; ++r)
            has[q * 4 + r][col] = acc[r];
    }
    __syncthreads();

    {   // fragment-layout conversion
        int kc = t >> 6, mm = (t >> 2) & 15, qq = t & 3;
        int cb = kc * 32 + qq * 8;
        us8 oh, oa;
        #pragma unroll
        for (int e = 0; e < 8; ++e) {
            oh[e] = f2bf(hs[mm][cb + e]);
            oa[e] = f2bf(has[mm][cb + e]);
        }
        size_t U = (size_t)(I0 >> 4) * 256 + kc * 64 + mm * 4 + qq;
        ((us8*)h16f)[U]  = oh;
        ((us8*)hA16f)[U] = oa;
    }
    __syncthreads();
}

// ================= phase 2: scores, 4 J-tiles per block, A-frag reuse =================
__device__ __forceinline__ void phase_scores(int L, int t, char* smem,
        const ushort* __restrict__ h16f, const ushort* __restrict__ hA16f,
        const u64* __restrict__ bm, ushort* __restrict__ Ef, float* __restrict__ Z) {
    float (*sc)[68] = (float(*)[68])smem;             // 17408 B
    float (*cz)[64] = (float(*)[64])(smem + 17408);   // 1024 B
    int b = L >> 6, Itile = (L >> 2) & 15, jgrp = L & 3;
    int I0 = Itile << 6;
    int wid = t >> 6, lane = t & 63, m = lane & 15, q = lane >> 4;
    int row16 = t >> 4, c = t & 15;

    const us8* Hf = (const us8*)h16f  + (size_t)b * 16384;
    const us8* Af = (const us8*)hA16f + (size_t)b * 16384;
    int off = m * 4 + q;
    int rtA = (I0 >> 4) + wid;

    us8 A1[4], A2[4];
    #pragma unroll
    for (int ks = 0; ks < 4; ++ks) {
        A1[ks] = Af[rtA * 256 + ks * 64 + off];
        A2[ks] = Hf[rtA * 256 + ks * 64 + off];
    }

    #pragma unroll 1
    for (int jj = 0; jj < 4; ++jj) {
        int J0 = (jgrp * 4 + jj) << 6;
        f32x4 acc[4] = {};
        #pragma unroll
        for (int ks = 0; ks < 4; ++ks) {
            short8 a1 = __builtin_bit_cast(short8, A1[ks]);
            short8 a2 = __builtin_bit_cast(short8, A2[ks]);
            #pragma unroll
            for (int nt = 0; nt < 4; ++nt) {
                int rtB = (J0 >> 4) + nt;
                short8 b1 = __builtin_bit_cast(short8, Hf[rtB * 256 + ks * 64 + off]);
                short8 b2 = __builtin_bit_cast(short8, Af[rtB * 256 + ks * 64 + off]);
                acc[nt] = __builtin_amdgcn_mfma_f32_16x16x32_bf16(a1, b1, acc[nt], 0, 0, 0);
                acc[nt] = __builtin_amdgcn_mfma_f32_16x16x32_bf16(a2, b2, acc[nt], 0, 0, 0);
            }
        }
        __syncthreads();                              // prior jj readers done
        #pragma unroll
        for (int nt = 0; nt < 4; ++nt)
            #pragma unroll
            for (int r = 0; r < 4; ++r)
                sc[wid * 16 + q * 4 + r][nt * 16 + m] = acc[nt][r];
        __syncthreads();

        int bitc = ((J0 >> 2) & 63) + c;
        float colsum[4] = {0.f, 0.f, 0.f, 0.f};
        #pragma unroll
        for (int it = 0; it < 4; ++it) {
            int row = it * 16 + row16;
            const u64* wp = bm + ((size_t)(b * Nn + I0 + row) * 4 + (J0 >> 8)) * 4;
            u64 wj[4] = {wp[0], wp[1], wp[2], wp[3]};
            float s4[4];
            *(float4*)s4 = *(const float4*)(&sc[row][c * 4]);
            us4 e4;
            #pragma unroll
            for (int j = 0; j < 4; ++j) {
                float ex = __expf(s4[j]);
                bool on = (wj[j] >> bitc) & 1;
                e4[j] = f2bf(on ? ex : 0.f);
                colsum[j] += on ? (ex - 1.0f) : 0.f;
            }
            size_t U = ((((size_t)b * 64 + Itile * 4 + it) * 32 + (J0 >> 5) + (c >> 3)) * 16 + row16) * 4
                     + ((c & 7) >> 1);
            *(us4*)(Ef + U * 8 + (c & 1) * 4) = e4;
        }
        #pragma unroll
        for (int j = 0; j < 4; ++j) {
            colsum[j] += __shfl_xor(colsum[j], 16, 64);
            colsum[j] += __shfl_xor(colsum[j], 32, 64);
        }
        if (lane < 16) {
            #pragma unroll
            for (int j = 0; j < 4; ++j) cz[wid][lane * 4 + j] = colsum[j];
        }
        __syncthreads();
        if (t < 64)
            atomicAdd(&Z[b * Nn + J0 + t], cz[0][t] + cz[1][t] + cz[2][t] + cz[3][t]);
    }
    __syncthreads();
}

// ================= phase 3: Tf0 = fragment-layout (h/Z)^T (blocks 0..255) =================
__device__ __forceinline__ void phase_prep(int L, int t, char* smem,
        const float* __restrict__ src, const float* __restrict__ Z,
        ushort* __restrict__ Tf) {
    if (L >= 256) return;
    float (*ls)[129] = (float(*)[129])smem;           // 33024 B
    float* iz = (float*)(smem + 33024);               // 256 B
    int b = L >> 4, j0 = (L & 15) * 64;
    if (t < 64) iz[t] = 1.0f / Z[b * Nn + j0 + t];
    __syncthreads();
    #pragma unroll
    for (int it = 0; it < 32; ++it) {
        int idx = it * 256 + t;
        int j = idx >> 7, k = idx & 127;
        ls[j][k] = src[((size_t)b * Nn + j0 + j) * Dn + k] * iz[j];
    }
    __syncthreads();
    int k = t & 127, half = t >> 7;
    us8 o[4];
    #pragma unroll
    for (int qq = 0; qq < 4; ++qq) {
        us8 tmp;
        #pragma unroll
        for (int e = 0; e < 8; ++e)
            tmp[e] = f2bf(ls[half * 32 + qq * 8 + e][k]);
        o[qq] = tmp;
    }
    size_t U = (((size_t)(k >> 4) * 32 + (j0 >> 5) + half) * 16 + (k & 15)) * 4;
    us8* dst = (us8*)(Tf + (size_t)b * 131072 + U * 8);
    dst[0] = o[0]; dst[1] = o[1]; dst[2] = o[2]; dst[3] = o[3];
}

// ================= phase 4/5/6: hop GEMM, waves split K, fused gate =================
__device__ __forceinline__ void phase_hop(int L, int t, char* smem,
        const ushort* __restrict__ Ef, const ushort* __restrict__ Tf,
        const float* __restrict__ h, const float* __restrict__ Z,
        const float* __restrict__ gw, const float* __restrict__ gb,
        ushort* __restrict__ Tfn, float* __restrict__ out, int last) {
    int b = L >> 6, rt = L & 63;                      // matches scores writer rows
    int I0 = rt << 4;
    int w = t >> 6, lane = t & 63;
    int m = lane & 15, q = lane >> 4;

    float (*red)[16][132] = (float(*)[16][132])smem;  // 33792 B
    ushort (*tt)[16] = (ushort(*)[16])(smem + 33792); // 4096 B

    const us8* pA = (const us8*)Ef + ((size_t)b * 64 + rt) * 2048;
    const us8* pB = (const us8*)Tf + (size_t)b * 16384;
    int off = m * 4 + q;

    f32x4 acc[8] = {};
    #pragma unroll 2
    for (int k8 = 0; k8 < 8; ++k8) {
        int kc = w * 8 + k8;
        short8 a = __builtin_bit_cast(short8, pA[kc * 64 + off]);
        #pragma unroll
        for (int nt = 0; nt < 8; ++nt)
            acc[nt] = __builtin_amdgcn_mfma_f32_16x16x32_bf16(
                a, __builtin_bit_cast(short8, pB[nt * 2048 + kc * 64 + off]), acc[nt], 0, 0, 0);
    }
    __syncthreads();                                  // smem free from previous phase use
    #pragma unroll
    for (int nt = 0; nt < 8; ++nt)
        #pragma unroll
        for (int r = 0; r < 4; ++r)
            red[w][q * 4 + r][nt * 16 + m] = acc[nt][r];
    __syncthreads();

    int row = t >> 4, c = t & 15;
    float gb0 = gb[0];
    float azv[8], hv[8];
    float gs = 0.f;
    size_t hbase = ((size_t)b * Nn + I0 + row) * Dn;
    #pragma unroll
    for (int j = 0; j < 8; ++j) {
        int k = c + 16 * j;
        float v = red[0][row][k] + red[1][row][k] + red[2][row][k] + red[3][row][k];
        v = fmaxf(v, 0.f);
        float hh = h[hbase + k];
        azv[j] = v; hv[j] = hh;
        gs += hh * gw[k] + v * gw[Dn + k];
    }
    gs += __shfl_xor(gs, 1, 64);
    gs += __shfl_xor(gs, 2, 64);
    gs += __shfl_xor(gs, 4, 64);
    gs += __shfl_xor(gs, 8, 64);
    float coef = 1.0f / (1.0f + __expf(-(gs + gb0)));

    if (last) {
        #pragma unroll
        for (int j = 0; j < 8; ++j)
            out[hbase + c + 16 * j] = coef * hv[j] + (1.f - coef) * azv[j];
    } else {
        float iz = 1.0f / Z[b * Nn + I0 + row];
        #pragma unroll
        for (int j = 0; j < 8; ++j)
            tt[c + 16 * j][row] = f2bf((coef * hv[j] + (1.f - coef) * azv[j]) * iz);
        __syncthreads();
        int k = t >> 1, part = t & 1;
        size_t U = ((size_t)b * 8 + (k >> 4)) * 2048 + (rt >> 1) * 64 + (k & 15) * 4
                 + ((rt & 1) << 1) + part;
        ((us8*)Tfn)[U] = *(const us8*)&tt[k][part * 8];
    }
    __syncthreads();
}

// ================= the single cooperative kernel =================
__global__ __launch_bounds__(256, 4) void k_mega(
        const float* x, const float* adj, const float* Ww, const float* Wb,
        const float* A, const float* gw, const float* gb, float* out,
        float* h, ushort* Ta, ushort* Tb, ushort* Ef, float* Z,
        ushort* Whi, ushort* Wlo, ushort* AThi, ushort* ATlo, u64* bm) {
    cg::grid_group g = cg::this_grid();
    int L = blockIdx.x, t = threadIdx.x;
    __shared__ __align__(16) char smem[38912];

    phase_wprep_pack(L, t, Ww, A, adj, Whi, Wlo, AThi, ATlo, Z, bm);
    g.sync();
    phase_h(L, t, smem, x, Wb, Whi, Wlo, AThi, ATlo, h, Ta, Tb);   // Ta=h16f, Tb=hA16f
    g.sync();
    phase_scores(L, t, smem, Ta, Tb, bm, Ef, Z);
    g.sync();
    phase_prep(L, t, smem, h, Z, Ta);                              // Tf0 -> Ta
    g.sync();
    phase_hop(L, t, smem, Ef, Ta, h, Z, gw, gb, Tb, out, 0);
    g.sync();
    phase_hop(L, t, smem, Ef, Tb, h, Z, gw, gb, Ta, out, 0);
    g.sync();
    phase_hop(L, t, smem, Ef, Ta, h, Z, gw, gb, (ushort*)nullptr, out, 1);
}

// ================= fallback standalone kernels (same phase code) =================
__global__ __launch_bounds__(256) void k_ph0(const float* Ww, const float* A, const float* adj,
        ushort* Whi, ushort* Wlo, ushort* AThi, ushort* ATlo, float* Z, u64* bm) {
    phase_wprep_pack(blockIdx.x, threadIdx.x, Ww, A, adj, Whi, Wlo, AThi, ATlo, Z, bm);
}
__global__ __launch_bounds__(256) void k_ph1(const float* x, const float* Wb,
        const ushort* Whi, const ushort* Wlo, const ushort* AThi, const ushort* ATlo,
        float* h, ushort* h16f, ushort* hA16f) {
    __shared__ __align__(16) char smem[16896];
    phase_h(blockIdx.x, threadIdx.x, smem, x, Wb, Whi, Wlo, AThi, ATlo, h, h16f, hA16f);
}
__global__ __launch_bounds__(256) void k_ph2(const ushort* h16f, const ushort* hA16f,
        const u64* bm, ushort* Ef, float* Z) {
    __shared__ __align__(16) char smem[18432];
    phase_scores(blockIdx.x, threadIdx.x, smem, h16f, hA16f, bm, Ef, Z);
}
__global__ __launch_bounds__(256) void k_ph3(const float* src, const float* Z, ushort* Tf) {
    __shared__ __align__(16) char smem[33280];
    phase_prep(blockIdx.x, threadIdx.x, smem, src, Z, Tf);
}
__global__ __launch_bounds__(256, 4) void k_ph4(const ushort* Ef, const ushort* Tf,
        const float* h, const float* Z, const float* gw, const float* gb,
        ushort* Tfn, float* out, int last) {
    __shared__ __align__(16) char smem[37888];
    phase_hop(blockIdx.x, threadIdx.x, smem, Ef, Tf, h, Z, gw, gb, Tfn, out, last);
}

extern "C" void kernel_launch(void* const* d_in, const int* in_sizes, int n_in,
                              void* d_out, int out_size, void* d_ws, size_t ws_size,
                              hipStream_t stream) {
    const float* x    = (const float*)d_in[0];   // [B,N,128]
    const float* adj  = (const float*)d_in[1];   // [B,N,N]
    const float* Ww   = (const float*)d_in[2];   // [128,128]
    const float* Wb   = (const float*)d_in[3];   // [128]
    const float* A    = (const float*)d_in[4];   // [128,128]
    const float* gw   = (const float*)d_in[5];   // [1,256]
    const float* gb   = (const float*)d_in[6];   // [1]
    float* out = (float*)d_out;                  // [B,N,128] f32

    char* ws = (char*)d_ws;
    float*  h    = (float*)(ws);                          // 8 MB f32
    ushort* Ta   = (ushort*)(ws + (8u << 20));            // 4 MB: h16f, then Tf buf A
    ushort* Tb   = (ushort*)(ws + (12u << 20));           // 4 MB: hA16f, then Tf buf B
    ushort* E    = (ushort*)(ws + (16u << 20));           // 32 MB (fragment layout)
    float*  Z    = (float*)(ws + (48u << 20));            // 64 KB
    ushort* Whi  = (ushort*)(ws + (48u << 20) + (64u << 10));
    ushort* Wlo  = (ushort*)(ws + (48u << 20) + (96u << 10));
    ushort* AThi = (ushort*)(ws + (48u << 20) + (128u << 10));
    ushort* ATlo = (ushort*)(ws + (48u << 20) + (160u << 10));
    u64*    bm   = (u64*)(ws + (48u << 20) + (192u << 10));  // 2 MB bitmask
    // total ~50.2 MB

    void* kargs[] = { (void*)&x, (void*)&adj, (void*)&Ww, (void*)&Wb, (void*)&A,
                      (void*)&gw, (void*)&gb, (void*)&out, (void*)&h, (void*)&Ta,
                      (void*)&Tb, (void*)&E, (void*)&Z, (void*)&Whi, (void*)&Wlo,
                      (void*)&AThi, (void*)&ATlo, (void*)&bm };
    hipError_t err = hipLaunchCooperativeKernel((const void*)k_mega,
                                                dim3(1024), dim3(256), kargs, 0, stream);
    if (err != hipSuccess) {
        (void)hipGetLastError();   // clear sticky error; fall back to split launches
        k_ph0<<<1024, 256, 0, stream>>>(Ww, A, adj, Whi, Wlo, AThi, ATlo, Z, bm);
        k_ph1<<<1024, 256, 0, stream>>>(x, Wb, Whi, Wlo, AThi, ATlo, h, Ta, Tb);
        k_ph2<<<1024, 256, 0, stream>>>(Ta, Tb, bm, E, Z);
        k_ph3<<<256,  256, 0, stream>>>(h, Z, Ta);
        k_ph4<<<1024, 256, 0, stream>>>(E, Ta, h, Z, gw, gb, Tb, out, 0);
        k_ph4<<<1024, 256, 0, stream>>>(E, Tb, h, Z, gw, gb, Ta, out, 0);
        k_ph4<<<1024, 256, 0, stream>>>(E, Ta, h, Z, gw, gb, (ushort*)nullptr, out, 1);
    }
}

// Round 12
// 228.887 us; speedup vs baseline: 4.4213x; 4.4213x over previous
//
#include <hip/hip_runtime.h>
#include <math.h>

#define Bn 16
#define Nn 1024
#define Dn 128

typedef unsigned short ushort;
typedef unsigned long long u64;
typedef short short8 __attribute__((ext_vector_type(8)));
typedef float f32x4 __attribute__((ext_vector_type(4)));
typedef ushort us8 __attribute__((ext_vector_type(8)));
typedef ushort us4 __attribute__((ext_vector_type(4)));

__device__ __forceinline__ ushort f2bf(float f) {
    unsigned u = __float_as_uint(f);
    u += 0x7fff + ((u >> 16) & 1);           // RTN-even
    return (ushort)(u >> 16);
}
__device__ __forceinline__ float bf2f(ushort s) {
    return __uint_as_float(((unsigned)s) << 16);
}

// ---- async global->LDS staging (m97 path). 16B/lane, LDS dst = uniform base + lane*16.
#if defined(__has_builtin)
#if __has_builtin(__builtin_amdgcn_global_load_lds)
#define HAVE_GLL 1
#endif
#endif
#ifndef HAVE_GLL
#define HAVE_GLL 0
#endif

typedef __attribute__((address_space(1))) void as1_t;
typedef __attribute__((address_space(3))) void as3_t;

__device__ __forceinline__ void stage_group(const void* gbase, void* lbase, int lane) {
#if HAVE_GLL
    __builtin_amdgcn_global_load_lds((as1_t*)((const char*)gbase + lane * 16),
                                     (as3_t*)lbase, 16, 0, 0);
#else
    *(us8*)((char*)lbase + lane * 16) = *(const us8*)((const char*)gbase + lane * 16);
#endif
}

// Fragment layouts (us8 units of 16 B), tile = 16 rows:
//   h16f/hA16f: unit = rt_global*256 + kc*64 + m*4 + q     (kc 0..3)
//   Ef:         unit = ((b*64 + rt)*32 + kc)*64 + m*4 + q  (kc 0..31)
//   Tf:         unit = ((b*8  + nt)*32 + kc)*64 + m*4 + q
// bm ballot layout: bm[(row_global*4 + chunk)*4 + j], chunk=col>>8, j=col&3, bit=(col>>2)&63

// ================= K0: weight split + Z init + adj ballot-pack (fused) =================
__global__ __launch_bounds__(256) void k_ph0(const float* __restrict__ Ww,
                                             const float* __restrict__ A,
                                             const float* __restrict__ adj,
                                             ushort* __restrict__ Whi, ushort* __restrict__ Wlo,
                                             ushort* __restrict__ AThi, ushort* __restrict__ ATlo,
                                             float* __restrict__ Z, u64* __restrict__ bm) {
    int L = blockIdx.x, t = threadIdx.x;
    if (L < 64) {
        int i = L * 256 + t;
        float w = Ww[i];
        ushort wh = f2bf(w);
        Whi[i] = wh;
        Wlo[i] = f2bf(w - bf2f(wh));
        int e = i >> 7, d = i & 127;
        float a = A[d * Dn + e];
        ushort ah = f2bf(a);
        AThi[i] = ah;
        ATlo[i] = f2bf(a - bf2f(ah));
        Z[i] = (float)Nn;                          // non-edge exp(0) mass, m=0 shift
    }
    int gwv = L * 4 + (t >> 6);
    int lane = t & 63;
    #pragma unroll 4
    for (int it = 0; it < 16; ++it) {
        int pair = gwv * 16 + it;                  // (row,chunk), 65536 total
        const float* p = adj + (size_t)pair * 256 + lane * 4;
        float4 v = *(const float4*)p;
        u64 b0 = __ballot(v.x > 0.f);
        u64 b1 = __ballot(v.y > 0.f);
        u64 b2 = __ballot(v.z > 0.f);
        u64 b3 = __ballot(v.w > 0.f);
        if (lane == 0) {
            u64* d = bm + (size_t)pair * 4;
            d[0] = b0; d[1] = b1; d[2] = b2; d[3] = b3;
        }
    }
}

// ================= K1: h = xW^T+b ; hA = h@A ; fragment bf16 out; x LDS-staged =================
__global__ __launch_bounds__(256) void k_h(const float* __restrict__ x,
                                           const float* __restrict__ Wb,
                                           const ushort* __restrict__ Whi,
                                           const ushort* __restrict__ Wlo,
                                           const ushort* __restrict__ AThi,
                                           const ushort* __restrict__ ATlo,
                                           float* __restrict__ h,
                                           ushort* __restrict__ h16f,
                                           ushort* __restrict__ hA16f) {
    int I0 = blockIdx.x * 16;
    int t = threadIdx.x, w = t >> 6, lane = t & 63;
    int m = lane & 15, q = lane >> 4;

    __shared__ float xs[16][Dn + 4];
    __shared__ float hs[16][Dn + 4];
    __shared__ float has[16][Dn + 4];

    {   // coalesced x stage: thread t -> row t>>4, cols (t&15)*8..+8
        int r = t >> 4, c8 = (t & 15) * 8;
        const float* src = x + (size_t)(I0 + r) * Dn + c8;
        *(float4*)&xs[r][c8]     = *(const float4*)(src);
        *(float4*)&xs[r][c8 + 4] = *(const float4*)(src + 4);
    }
    __syncthreads();

    f32x4 acc0 = {0,0,0,0}, acc1 = {0,0,0,0};
    #pragma unroll
    for (int ks = 0; ks < 4; ++ks) {
        int k0 = q * 8 + ks * 32;
        float v[8]; short8 ahi, alo;
        *(float4*)(v)     = *(const float4*)(&xs[m][k0]);
        *(float4*)(v + 4) = *(const float4*)(&xs[m][k0 + 4]);
        #pragma unroll
        for (int j = 0; j < 8; ++j) {
            ushort hi = f2bf(v[j]);
            ahi[j] = (short)hi;
            alo[j] = (short)f2bf(v[j] - bf2f(hi));
        }
        #pragma unroll
        for (int nn = 0; nn < 2; ++nn) {
            int brow = (w * 2 + nn) * 16 + m;
            short8 bhi = __builtin_bit_cast(short8, ((const us8*)(Whi + (size_t)brow * Dn))[q + ks * 4]);
            short8 blo = __builtin_bit_cast(short8, ((const us8*)(Wlo + (size_t)brow * Dn))[q + ks * 4]);
            f32x4 acc = nn ? acc1 : acc0;
            acc = __builtin_amdgcn_mfma_f32_16x16x32_bf16(ahi, bhi, acc, 0, 0, 0);
            acc = __builtin_amdgcn_mfma_f32_16x16x32_bf16(alo, bhi, acc, 0, 0, 0);
            acc = __builtin_amdgcn_mfma_f32_16x16x32_bf16(ahi, blo, acc, 0, 0, 0);
            if (nn) acc1 = acc; else acc0 = acc;
        }
    }
    #pragma unroll
    for (int nn = 0; nn < 2; ++nn) {
        int col = (w * 2 + nn) * 16 + m;
        float bias = Wb[col];
        f32x4 acc = nn ? acc1 : acc0;
        #pragma unroll
        for (int r = 0; r < 4; ++r) {
            int rl = q * 4 + r;
            float hv = acc[r] + bias;
            h[(size_t)(I0 + rl) * Dn + col] = hv;
            hs[rl][col] = hv;
        }
    }
    __syncthreads();

    f32x4 bcc0 = {0,0,0,0}, bcc1 = {0,0,0,0};
    #pragma unroll
    for (int ks = 0; ks < 4; ++ks) {
        int k0 = q * 8 + ks * 32;
        float v[8]; short8 ahi, alo;
        *(float4*)(v)     = *(const float4*)(&hs[m][k0]);
        *(float4*)(v + 4) = *(const float4*)(&hs[m][k0 + 4]);
        #pragma unroll
        for (int j = 0; j < 8; ++j) {
            ushort hi = f2bf(v[j]);
            ahi[j] = (short)hi;
            alo[j] = (short)f2bf(v[j] - bf2f(hi));
        }
        #pragma unroll
        for (int nn = 0; nn < 2; ++nn) {
            int brow = (w * 2 + nn) * 16 + m;
            short8 bhi = __builtin_bit_cast(short8, ((const us8*)(AThi + (size_t)brow * Dn))[q + ks * 4]);
            short8 blo = __builtin_bit_cast(short8, ((const us8*)(ATlo + (size_t)brow * Dn))[q + ks * 4]);
            f32x4 acc = nn ? bcc1 : bcc0;
            acc = __builtin_amdgcn_mfma_f32_16x16x32_bf16(ahi, bhi, acc, 0, 0, 0);
            acc = __builtin_amdgcn_mfma_f32_16x16x32_bf16(alo, bhi, acc, 0, 0, 0);
            acc = __builtin_amdgcn_mfma_f32_16x16x32_bf16(ahi, blo, acc, 0, 0, 0);
            if (nn) bcc1 = acc; else bcc0 = acc;
        }
    }
    #pragma unroll
    for (int nn = 0; nn < 2; ++nn) {
        int col = (w * 2 + nn) * 16 + m;
        f32x4 acc = nn ? bcc1 : bcc0;
        #pragma unroll
        for (int r = 0; r < 4; ++r)
            has[q * 4 + r][col] = acc[r];
    }
    __syncthreads();

    {   // fragment-layout conversion: thread t -> one us8 of h16f and hA16f
        int kc = t >> 6, mm = (t >> 2) & 15, qq = t & 3;
        int cb = kc * 32 + qq * 8;
        us8 oh, oa;
        #pragma unroll
        for (int e = 0; e < 8; ++e) {
            oh[e] = f2bf(hs[mm][cb + e]);
            oa[e] = f2bf(has[mm][cb + e]);
        }
        size_t U = (size_t)(I0 >> 4) * 256 + kc * 64 + mm * 4 + qq;
        ((us8*)h16f)[U]  = oh;
        ((us8*)hA16f)[U] = oa;
    }
}

// ================= K3: scores with async-LDS staged fragments (m97 structure) =================
__global__ __launch_bounds__(256, 2) void k_scores(const ushort* __restrict__ h16f,
                                                   const ushort* __restrict__ hA16f,
                                                   const u64* __restrict__ bm,
                                                   ushort* __restrict__ Ef,
                                                   float* __restrict__ Z) {
    int L = blockIdx.x;
    int b    = ((L & 7) << 1) | (L >> 11);        // XCD-grouped batches
    int tile = (L >> 3) & 255;
    int I0 = (tile >> 4) << 6;
    int J0 = (tile & 15) << 6;
    int t = threadIdx.x, wid = t >> 6, lane = t & 63;
    int m = lane & 15, q = lane >> 4;

    __shared__ __align__(16) char smem[66560];    // 64K stage (IH,IA,JH,JA) + 1K cz
    float (*sc)[68] = (float(*)[68])smem;         // aliases stage after MFMA
    float (*cz)[64] = (float(*)[64])(smem + 65536);

    // stage 64 x 1KB groups: arr = g>>4 in {IH,IA,JH,JA}; rt_l=(g>>2)&3; kk=g&3
    {
        const char* hb  = (const char*)h16f  + (size_t)b * 16384 * 16;
        const char* ab  = (const char*)hA16f + (size_t)b * 16384 * 16;
        for (int g = wid; g < 64; g += 4) {
            int arr = g >> 4, rt_l = (g >> 2) & 3, kk = g & 3;
            int rbase = ((arr < 2) ? (I0 >> 4) : (J0 >> 4)) + rt_l;
            const char* base = (arr & 1) ? ab : hb;
            const char* gp = base + ((size_t)rbase * 256 + kk * 64) * 16;
            stage_group(gp, smem + g * 1024, lane);
        }
    }
    __syncthreads();                              // drains vmcnt -> staged data visible

    int off16 = (m * 4 + q) * 16;
    f32x4 acc[4] = {};
    #pragma unroll
    for (int ks = 0; ks < 4; ++ks) {
        short8 a1 = __builtin_bit_cast(short8, *(const us8*)(smem + 16384 + (wid * 4 + ks) * 1024 + off16)); // hA_I
        short8 a2 = __builtin_bit_cast(short8, *(const us8*)(smem +         (wid * 4 + ks) * 1024 + off16)); // h_I
        #pragma unroll
        for (int nt = 0; nt < 4; ++nt) {
            short8 b1 = __builtin_bit_cast(short8, *(const us8*)(smem + 32768 + (nt * 4 + ks) * 1024 + off16)); // h_J
            short8 b2 = __builtin_bit_cast(short8, *(const us8*)(smem + 49152 + (nt * 4 + ks) * 1024 + off16)); // hA_J
            acc[nt] = __builtin_amdgcn_mfma_f32_16x16x32_bf16(a1, b1, acc[nt], 0, 0, 0);
            acc[nt] = __builtin_amdgcn_mfma_f32_16x16x32_bf16(a2, b2, acc[nt], 0, 0, 0);
        }
    }
    __syncthreads();                              // staging dead; alias as sc

    #pragma unroll
    for (int nt = 0; nt < 4; ++nt)
        #pragma unroll
        for (int r = 0; r < 4; ++r)
            sc[wid * 16 + q * 4 + r][nt * 16 + m] = acc[nt][r];
    __syncthreads();

    int row16 = t >> 4, c = t & 15;
    int bitc = ((J0 >> 2) & 63) + c;
    float colsum[4] = {0.f, 0.f, 0.f, 0.f};
    #pragma unroll
    for (int it = 0; it < 4; ++it) {
        int row = it * 16 + row16;
        const u64* wp = bm + ((size_t)(b * Nn + I0 + row) * 4 + (J0 >> 8)) * 4;
        u64 wj[4] = {wp[0], wp[1], wp[2], wp[3]};
        float s4[4];
        *(float4*)s4 = *(const float4*)(&sc[row][c * 4]);
        us4 e4;
        #pragma unroll
        for (int j = 0; j < 4; ++j) {
            float ex = __expf(s4[j]);
            bool on = (wj[j] >> bitc) & 1;
            e4[j] = f2bf(on ? ex : 0.f);
            colsum[j] += on ? (ex - 1.0f) : 0.f;
        }
        size_t U = ((((size_t)b * 64 + (I0 >> 4) + it) * 32 + (J0 >> 5) + (c >> 3)) * 16 + row16) * 4
                 + ((c & 7) >> 1);
        *(us4*)(Ef + U * 8 + (c & 1) * 4) = e4;
    }
    #pragma unroll
    for (int j = 0; j < 4; ++j) {
        colsum[j] += __shfl_xor(colsum[j], 16, 64);
        colsum[j] += __shfl_xor(colsum[j], 32, 64);
    }
    if (lane < 16) {
        #pragma unroll
        for (int j = 0; j < 4; ++j) cz[wid][lane * 4 + j] = colsum[j];
    }
    __syncthreads();
    if (t < 64) {
        float s = cz[0][t] + cz[1][t] + cz[2][t] + cz[3][t];
        atomicAdd(&Z[b * Nn + J0 + t], s);
    }
}

// ================= K4: Tf = fragment-layout (src/Z)^T =================
__global__ __launch_bounds__(256) void k_prep(const float* __restrict__ src,
                                              const float* __restrict__ Z,
                                              ushort* __restrict__ Tf) {
    int b = blockIdx.y;
    int j0 = blockIdx.x * 64;
    int t = threadIdx.x;
    __shared__ float ls[64][129];
    __shared__ float iz[64];
    if (t < 64) iz[t] = 1.0f / Z[b * Nn + j0 + t];
    __syncthreads();
    #pragma unroll
    for (int it = 0; it < 8; ++it) {              // float4 coalesced in
        int idx = it * 256 + t;
        int j = idx >> 5, k4 = (idx & 31) * 4;
        float4 v = *(const float4*)(src + ((size_t)b * Nn + j0 + j) * Dn + k4);
        float z = iz[j];
        ls[j][k4] = v.x * z; ls[j][k4 + 1] = v.y * z;
        ls[j][k4 + 2] = v.z * z; ls[j][k4 + 3] = v.w * z;
    }
    __syncthreads();
    int k = t & 127, half = t >> 7;
    us8 o[4];
    #pragma unroll
    for (int qq = 0; qq < 4; ++qq) {
        us8 tmp;
        #pragma unroll
        for (int e = 0; e < 8; ++e)
            tmp[e] = f2bf(ls[half * 32 + qq * 8 + e][k]);
        o[qq] = tmp;
    }
    size_t U = (((size_t)(k >> 4) * 32 + (j0 >> 5) + half) * 16 + (k & 15)) * 4;
    us8* dst = (us8*)(Tf + (size_t)b * 131072 + U * 8);
    dst[0] = o[0]; dst[1] = o[1]; dst[2] = o[2]; dst[3] = o[3];
}

// ================= K5: hop GEMM, m97 structure: async-LDS chunks, wave=16 rows x 128 cols ==========
__global__ __launch_bounds__(256) void k_hop(const ushort* __restrict__ Ef,
                                             const ushort* __restrict__ Tf,
                                             const float* __restrict__ h,
                                             const float* __restrict__ Z,
                                             const float* __restrict__ gw,
                                             const float* __restrict__ gb,
                                             ushort* __restrict__ Tfn,
                                             float* __restrict__ out,
                                             int last) {
    int L = blockIdx.x;                           // 256 blocks
    int b  = ((L & 7) << 1) | (L >> 7);           // 8 XCDs x 2 batches
    int t4 = (L >> 3) & 15;                       // 64-row tile
    int t = threadIdx.x, w = t >> 6, lane = t & 63;
    int m = lane & 15, q = lane >> 4;
    int rt = t4 * 4 + w;                          // wave's 16-row MFMA tile
    int I0 = rt << 4;

    __shared__ __align__(16) char smem[49152];    // A 16K + B 32K; tt aliases after K-loop
    int off16 = (m * 4 + q) * 16;

    f32x4 acc[8] = {};
    for (int cch = 0; cch < 8; ++cch) {           // K chunks of 128
        // stage 48 x 1KB groups: g<16: A (rr=g>>2, kk=g&3); else B (nt=(g-16)>>2, kk=(g-16)&3)
        for (int g = w; g < 48; g += 4) {
            const char* gp; char* lp;
            if (g < 16) {
                int rr = g >> 2, kk = g & 3;
                gp = (const char*)Ef + ((((size_t)b * 64 + t4 * 4 + rr) * 32 + cch * 4 + kk) * 64) * 16;
                lp = smem + g * 1024;
            } else {
                int gb2 = g - 16, nt = gb2 >> 2, kk = gb2 & 3;
                gp = (const char*)Tf + ((((size_t)b * 8 + nt) * 32 + cch * 4 + kk) * 64) * 16;
                lp = smem + 16384 + gb2 * 1024;
            }
            stage_group(gp, lp, lane);
        }
        __syncthreads();                          // vmcnt drain -> data ready

        #pragma unroll
        for (int kk = 0; kk < 4; ++kk) {
            short8 a = __builtin_bit_cast(short8, *(const us8*)(smem + (w * 4 + kk) * 1024 + off16));
            #pragma unroll
            for (int nt = 0; nt < 8; ++nt) {
                short8 bf = __builtin_bit_cast(short8,
                    *(const us8*)(smem + 16384 + (nt * 4 + kk) * 1024 + off16));
                acc[nt] = __builtin_amdgcn_mfma_f32_16x16x32_bf16(a, bf, acc[nt], 0, 0, 0);
            }
        }
        __syncthreads();                          // readers done before restage
    }

    // epilogue (R9-verified): wave-local relu+gate+lerp
    float gb0 = gb[0];
    float gwa[8], gwz[8];
    #pragma unroll
    for (int nt = 0; nt < 8; ++nt) { gwa[nt] = gw[nt * 16 + m]; gwz[nt] = gw[Dn + nt * 16 + m]; }

    float hv[8][4], coef[4];
    size_t hbase = ((size_t)b * Nn + I0) * Dn;
    #pragma unroll
    for (int r = 0; r < 4; ++r) {
        int row = q * 4 + r;
        float gs = 0.f;
        #pragma unroll
        for (int nt = 0; nt < 8; ++nt) {
            float az = fmaxf(acc[nt][r], 0.f);
            acc[nt][r] = az;
            float hh = h[hbase + (size_t)row * Dn + nt * 16 + m];
            hv[nt][r] = hh;
            gs += hh * gwa[nt] + az * gwz[nt];
        }
        gs += __shfl_xor(gs, 1, 64);
        gs += __shfl_xor(gs, 2, 64);
        gs += __shfl_xor(gs, 4, 64);
        gs += __shfl_xor(gs, 8, 64);              // sum over the 16 m-lanes
        coef[r] = 1.0f / (1.0f + __expf(-(gs + gb0)));
    }

    if (last) {
        #pragma unroll
        for (int r = 0; r < 4; ++r) {
            int row = q * 4 + r;
            float cc = coef[r];
            #pragma unroll
            for (int nt = 0; nt < 8; ++nt)
                out[hbase + (size_t)row * Dn + nt * 16 + m] =
                    cc * hv[nt][r] + (1.f - cc) * acc[nt][r];
        }
    } else {
        ushort (*tt)[128][16] = (ushort(*)[128][16])smem;   // 16 KB, aliases stage buf
        #pragma unroll
        for (int r = 0; r < 4; ++r) {
            int row = q * 4 + r;
            float cc = coef[r];
            float iz = 1.0f / Z[b * Nn + I0 + row];
            #pragma unroll
            for (int nt = 0; nt < 8; ++nt) {
                float v = cc * hv[nt][r] + (1.f - cc) * acc[nt][r];
                tt[w][nt * 16 + m][row] = f2bf(v * iz);
            }
        }
        __syncthreads();
        // fragment-layout Tf write: thread (k, jh) -> 64B contiguous (4 us8 units)
        int k = t >> 1, jh = t & 1;
        size_t U0 = (((size_t)(k >> 4) * 32 + t4 * 2 + jh) * 16 + (k & 15)) * 4;
        ushort* dst = Tfn + (size_t)b * 131072 + U0 * 8;
        #pragma unroll
        for (int qq = 0; qq < 4; ++qq)
            *(us8*)(dst + qq * 8) = *(const us8*)&tt[jh * 2 + (qq >> 1)][k][(qq & 1) * 8];
    }
}

extern "C" void kernel_launch(void* const* d_in, const int* in_sizes, int n_in,
                              void* d_out, int out_size, void* d_ws, size_t ws_size,
                              hipStream_t stream) {
    const float* x    = (const float*)d_in[0];   // [B,N,128]
    const float* adj  = (const float*)d_in[1];   // [B,N,N]
    const float* Ww   = (const float*)d_in[2];   // [128,128]
    const float* Wb   = (const float*)d_in[3];   // [128]
    const float* A    = (const float*)d_in[4];   // [128,128]
    const float* gw   = (const float*)d_in[5];   // [1,256]
    const float* gb   = (const float*)d_in[6];   // [1]
    float* out = (float*)d_out;                  // [B,N,128] f32

    char* ws = (char*)d_ws;
    float*  h    = (float*)(ws);                          // 8 MB f32
    ushort* Ta   = (ushort*)(ws + (8u << 20));            // 4 MB: h16f, then Tf buf A
    ushort* Tb   = (ushort*)(ws + (12u << 20));           // 4 MB: hA16f, then Tf buf B
    ushort* E    = (ushort*)(ws + (16u << 20));           // 32 MB (fragment layout)
    float*  Z    = (float*)(ws + (48u << 20));            // 64 KB
    ushort* Whi  = (ushort*)(ws + (48u << 20) + (64u << 10));
    ushort* Wlo  = (ushort*)(ws + (48u << 20) + (96u << 10));
    ushort* AThi = (ushort*)(ws + (48u << 20) + (128u << 10));
    ushort* ATlo = (ushort*)(ws + (48u << 20) + (160u << 10));
    u64*    bm   = (u64*)(ws + (48u << 20) + (192u << 10));  // 2 MB bitmask
    // total ~50.2 MB

    k_ph0   <<<1024, 256, 0, stream>>>(Ww, A, adj, Whi, Wlo, AThi, ATlo, Z, bm);
    k_h     <<<1024, 256, 0, stream>>>(x, Wb, Whi, Wlo, AThi, ATlo, h, Ta, Tb);
    k_scores<<<4096, 256, 0, stream>>>(Ta, Tb, bm, E, Z);
    k_prep  <<<dim3(16, Bn), 256, 0, stream>>>(h, Z, Ta);          // Tf0 = (h/Z)^T
    k_hop   <<<256, 256, 0, stream>>>(E, Ta, h, Z, gw, gb, Tb, out, 0);
    k_hop   <<<256, 256, 0, stream>>>(E, Tb, h, Z, gw, gb, Ta, out, 0);
    k_hop   <<<256, 256, 0, stream>>>(E, Ta, h, Z, gw, gb, (ushort*)nullptr, out, 1);
}